// Round 1
// baseline (911.548 us; speedup 1.0000x reference)
//
#include <hip/hip_runtime.h>

// ConvSE3 fused kernel (fp32 baseline).
// E = 160000 edges, N = 10000 nodes, C = 16, MID = 32.
// Pairs in input order: p0="00"(f0->deg0,K=16,DO=1) p1="01"(f0->deg1,K=16,DO=3)
//                       p2="10"(f1->deg0,K=16,DO=1) p3="11"(f1->deg1,K=48,DO=3)
// rw column semantics: col = c_out*K + k, k = c_in*nf + f  (K = C*nf).

#define BLOCK 256
constexpr int TE = 16;   // edges per block tile (E % TE == 0)

template<int K, int DO, int NCOLS, int SLOT>
__device__ __forceinline__ void pair_conv(
    const float* __restrict__ w3,     // [32][NCOLS] row-major
    const float* __restrict__ h2sp,   // LDS [TE][32]
    const float* __restrict__ tsp,    // LDS [TE][K][DO]
    float* __restrict__ oacc,         // LDS [TE][16][4]
    int wid, int lane)
{
  const int c_out = wid * 4 + (lane >> 4);   // 4 c_out per wave, disjoint across waves
  const int klo   = lane & 15;
  #pragma unroll
  for (int kc = 0; kc < K / 16; ++kc) {
    const int col = c_out * K + kc * 16 + klo;
    float w3r[32];
    #pragma unroll
    for (int m = 0; m < 32; ++m) w3r[m] = w3[m * NCOLS + col];  // coalesced, L2-hot
    for (int e = 0; e < TE; ++e) {
      const float* h2e = h2sp + e * 32;       // wave-uniform -> LDS broadcast reads
      float acc = 0.f;
      #pragma unroll
      for (int m = 0; m < 32; ++m) acc = fmaf(w3r[m], h2e[m], acc);
      const int k = kc * 16 + klo;
      float part[DO];
      #pragma unroll
      for (int d = 0; d < DO; ++d) part[d] = acc * tsp[(e * K + k) * DO + d];
      // reduce over the 16 k-lanes (xor bits 0..3 stay inside the group)
      #pragma unroll
      for (int s = 1; s < 16; s <<= 1) {
        #pragma unroll
        for (int d = 0; d < DO; ++d) part[d] += __shfl_xor(part[d], s);
      }
      if (klo == 0) {                          // unique owner per (e,c_out,slot): no race
        #pragma unroll
        for (int d = 0; d < DO; ++d)
          oacc[(e * 16 + c_out) * 4 + SLOT + d] += part[d];
      }
    }
  }
}

__global__ __launch_bounds__(BLOCK) void conv_se3_kernel(
    const float* __restrict__ feat0,
    const float* __restrict__ feat1,
    const float* __restrict__ edge_inv,
    const int*   __restrict__ src,
    const int*   __restrict__ dst,
    const float* __restrict__ b00,
    const float* __restrict__ b01,
    const float* __restrict__ b10,
    const float* __restrict__ b11,
    const float* __restrict__ w1_0, const float* __restrict__ bb1_0,
    const float* __restrict__ w2_0, const float* __restrict__ bb2_0,
    const float* __restrict__ w3_0,
    const float* __restrict__ w1_1, const float* __restrict__ bb1_1,
    const float* __restrict__ w2_1, const float* __restrict__ bb2_1,
    const float* __restrict__ w3_1,
    const float* __restrict__ w1_2, const float* __restrict__ bb1_2,
    const float* __restrict__ w2_2, const float* __restrict__ bb2_2,
    const float* __restrict__ w3_2,
    const float* __restrict__ w1_3, const float* __restrict__ bb1_3,
    const float* __restrict__ w2_3, const float* __restrict__ bb2_3,
    const float* __restrict__ w3_3,
    float* __restrict__ out)
{
  __shared__ float eis[TE][2];
  __shared__ int   ssrc[TE];
  __shared__ int   sdst[TE];
  __shared__ float h1s[4][TE][32];
  __shared__ float h2s[4][TE][32];
  __shared__ float sf0[TE][16];
  __shared__ float sf1[TE][48];     // [c][i]
  __shared__ float sb00[TE];
  __shared__ float sb01[TE][3];
  __shared__ float sb10[TE][3];
  __shared__ float sb11[TE][27];    // [i][f][do]
  __shared__ float ts0[TE][16];
  __shared__ float ts1[TE][16][3];
  __shared__ float ts2[TE][16];
  __shared__ float ts3[TE][48][3];
  __shared__ float oacc[TE][16][4];

  const int t  = threadIdx.x;
  const int e0 = blockIdx.x * TE;

  // ---- P0: stage per-edge scalars, zero the output accumulator ----
  for (int i = t; i < TE * 2; i += BLOCK) ((float*)eis)[i] = edge_inv[e0 * 2 + i];
  if (t < TE) { ssrc[t] = src[e0 + t]; sdst[t] = dst[e0 + t]; sb00[t] = b00[e0 + t]; }
  for (int i = t; i < TE * 3; i += BLOCK) {
    ((float*)sb01)[i] = b01[e0 * 3 + i];
    ((float*)sb10)[i] = b10[e0 * 3 + i];
  }
  for (int i = t; i < TE * 27; i += BLOCK) ((float*)sb11)[i] = b11[e0 * 27 + i];
  for (int i = t; i < TE * 64; i += BLOCK) ((float*)oacc)[i] = 0.f;
  __syncthreads();

  // ---- P1a: h1 = relu(edge_inv @ W1 + b1), all 4 pairs ----
  {
    const float* w1t[4] = {w1_0, w1_1, w1_2, w1_3};
    const float* b1t[4] = {bb1_0, bb1_1, bb1_2, bb1_3};
    const int combo = t & 127, p = combo >> 5, m = combo & 31, eb = (t >> 7) * 8;
    const float wa = w1t[p][m], wb = w1t[p][32 + m], bv = b1t[p][m];
    #pragma unroll
    for (int ee = 0; ee < 8; ++ee) {
      const int e = eb + ee;
      const float v = fmaf(eis[e][0], wa, fmaf(eis[e][1], wb, bv));
      h1s[p][e][m] = v > 0.f ? v : 0.f;
    }
  }
  // ---- P2a: gather source-node features ----
  for (int i = t; i < TE * 16; i += BLOCK) {
    const int e = i >> 4;
    sf0[e][i & 15] = feat0[ssrc[e] * 16 + (i & 15)];
  }
  for (int i = t; i < TE * 48; i += BLOCK) {
    const int e = i / 48;
    sf1[e][i % 48] = feat1[ssrc[e] * 48 + (i % 48)];
  }
  __syncthreads();

  // ---- P1b: h2 = relu(h1 @ W2 + b2) ----
  {
    const float* w2t[4] = {w2_0, w2_1, w2_2, w2_3};
    const float* b2t[4] = {bb2_0, bb2_1, bb2_2, bb2_3};
    const int combo = t & 127, p = combo >> 5, m = combo & 31, eb = (t >> 7) * 8;
    const float* w2 = w2t[p];
    const float bv = b2t[p][m];
    float acc[8];
    #pragma unroll
    for (int ee = 0; ee < 8; ++ee) acc[ee] = bv;
    for (int i = 0; i < 32; ++i) {
      const float wv = w2[i * 32 + m];
      #pragma unroll
      for (int ee = 0; ee < 8; ++ee) acc[ee] = fmaf(h1s[p][eb + ee][i], wv, acc[ee]);
    }
    #pragma unroll
    for (int ee = 0; ee < 8; ++ee) h2s[p][eb + ee][m] = acc[ee] > 0.f ? acc[ee] : 0.f;
  }
  // ---- P2b: tmp = einsum('eci,eifo->e(ci f)o', feats, basis) ----
  for (int i = t; i < TE * 16; i += BLOCK) {
    const int e = i >> 4, k = i & 15;
    ts0[e][k] = sf0[e][k] * sb00[e];
    float a = 0.f;
    #pragma unroll
    for (int ii = 0; ii < 3; ++ii) a = fmaf(sf1[e][k * 3 + ii], sb10[e][ii], a);
    ts2[e][k] = a;
  }
  for (int i = t; i < TE * 48; i += BLOCK) {
    const int e = i / 48, r = i % 48, k = r / 3, dd = r % 3;
    ts1[e][k][dd] = sf0[e][k] * sb01[e][dd];
  }
  for (int i = t; i < TE * 144; i += BLOCK) {
    const int e = i / 144, r = i % 144, k = r / 3, dd = r % 3, ci = k / 3, f = k % 3;
    float a = 0.f;
    #pragma unroll
    for (int ii = 0; ii < 3; ++ii)
      a = fmaf(sf1[e][ci * 3 + ii], sb11[e][ii * 9 + f * 3 + dd], a);
    ts3[e][k][dd] = a;
  }
  __syncthreads();

  // ---- P3: out[e,c_out,do] = sum_k (h2 @ W3)[c_out,k] * tmp[k,do] ----
  const int wid = t >> 6, lane = t & 63;
  pair_conv<16, 1, 256, 0>(w3_0, &h2s[0][0][0], &ts0[0][0],    &oacc[0][0][0], wid, lane);
  pair_conv<16, 3, 256, 1>(w3_1, &h2s[1][0][0], &ts1[0][0][0], &oacc[0][0][0], wid, lane);
  pair_conv<16, 1, 256, 0>(w3_2, &h2s[2][0][0], &ts2[0][0],    &oacc[0][0][0], wid, lane);
  pair_conv<48, 3, 768, 1>(w3_3, &h2s[3][0][0], &ts3[0][0][0], &oacc[0][0][0], wid, lane);
  __syncthreads();

  // ---- P4: scatter-sum into destination nodes, out layout [N][16][4] ----
  for (int i = t; i < TE * 64; i += BLOCK) {
    const int e = i >> 6;
    atomicAdd(&out[(size_t)sdst[e] * 64 + (i & 63)], ((const float*)oacc)[i]);
  }
}

extern "C" void kernel_launch(void* const* d_in, const int* in_sizes, int n_in,
                              void* d_out, int out_size, void* d_ws, size_t ws_size,
                              hipStream_t stream)
{
  const float* feat0    = (const float*)d_in[0];
  const float* feat1    = (const float*)d_in[1];
  const float* edge_inv = (const float*)d_in[2];
  const int*   src      = (const int*)d_in[3];
  const int*   dst      = (const int*)d_in[4];
  const float* b00      = (const float*)d_in[5];
  const float* b01      = (const float*)d_in[6];
  const float* b10      = (const float*)d_in[7];
  const float* b11      = (const float*)d_in[8];
  const float* w1[4]; const float* bb1[4]; const float* w2[4]; const float* bb2[4]; const float* w3[4];
  for (int p = 0; p < 4; ++p) {   // dict order: 00, 01, 10, 11
    w1[p]  = (const float*)d_in[9 + 5 * p + 0];
    bb1[p] = (const float*)d_in[9 + 5 * p + 1];
    w2[p]  = (const float*)d_in[9 + 5 * p + 2];
    bb2[p] = (const float*)d_in[9 + 5 * p + 3];
    w3[p]  = (const float*)d_in[9 + 5 * p + 4];
  }
  float* out = (float*)d_out;
  const int E = in_sizes[3];          // 160000, divisible by TE=16

  // harness re-poisons d_out to 0xAA before every launch -> zero it here
  hipMemsetAsync(d_out, 0, (size_t)out_size * sizeof(float), stream);

  const int nblocks = E / TE;
  hipLaunchKernelGGL(conv_se3_kernel, dim3(nblocks), dim3(BLOCK), 0, stream,
      feat0, feat1, edge_inv, src, dst, b00, b01, b10, b11,
      w1[0], bb1[0], w2[0], bb2[0], w3[0],
      w1[1], bb1[1], w2[1], bb2[1], w3[1],
      w1[2], bb1[2], w2[2], bb2[2], w3[2],
      w1[3], bb1[3], w2[3], bb2[3], w3[3],
      out);
}

// Round 7
// 436.746 us; speedup vs baseline: 2.0871x; 2.0871x over previous
//
#include <hip/hip_runtime.h>
#include <hip/hip_bf16.h>

// ConvSE3 fused — standard-orientation MFMA + LDS rw staging + scalar contraction.
// E=160000, N=10000, C=16, MID=32, TE=16 edges/block.
// Pairs: p0="00"(K=16,DO=1,slot0) p1="01"(K=16,DO=3,slot1..3)
//        p2="10"(K=16,DO=1,slot0) p3="11"(K=48,DO=3,slot1..3)
// rw col = c_out*K + k, k = c_in*nf + f.
// GEMM: D[edge][w3col] = sum_m h2[edge][m] * w3[m][col]   (A=h2, B=w3)
//   A-frag: lane&15 = edge row, k = 8*(lane>>4)+j  (contiguous LDS shorts)
//   B-frag: lane&15 = col,       k = 8*(lane>>4)+j  (strided global fp32, split)
//   D: col = lane&15 (= w3col), row = 4*(lane>>4)+reg (= edge)  [m89-verified]
// Split-bf16: v = hi(truncate) + lo(rtn residual); D += Ah*Bl + Al*Bh + Ah*Bh.
// rw staged in LDS; contraction out[e][co][dd] = sum_k rw[e][co*K+k]*tmp[e][k][dd]
// done per-thread (t>>4 = e, t&15 = co): no cross-lane ops at all.

#define BLOCK 256
constexpr int TE = 16;

typedef __attribute__((ext_vector_type(8))) short short8;
typedef __attribute__((ext_vector_type(4))) float f32x4;

__device__ __forceinline__ unsigned short f2b(float x) {
  return __builtin_bit_cast(unsigned short, __float2bfloat16(x));
}

// ---- LDS pool offsets (bytes). PERS lives whole kernel; EARLY aliases rws. ----
// PERS:   ssrc@0(64) sdst@64(64) h2hi@128(4096) h2lo@4224(4096)
//         ts0@8320(1280) ts1@9600(3328) ts2@12928(1280) ts3@14208(9472)
// LATE:   rws@23680 float[16][388] (24832)  -> total 48512
// EARLY(alias rws): eis@23680(128) h1s@23808(8448) sf0@32256(1024)
//         sf1@33280(3072) sb00@36352(64) sb01@36416(192) sb10@36608(192)
//         sb11@36800(1728) -> ends 38528 < 48512
constexpr int SMEM_BYTES = 48512;
constexpr int RWS_STRIDE = 388;   // floats per rws row (384 used max + pad)

__global__ __launch_bounds__(BLOCK) void conv_se3_kernel(
    const float* __restrict__ feat0,
    const float* __restrict__ feat1,
    const float* __restrict__ edge_inv,
    const int*   __restrict__ src,
    const int*   __restrict__ dst,
    const float* __restrict__ b00,
    const float* __restrict__ b01,
    const float* __restrict__ b10,
    const float* __restrict__ b11,
    const float* __restrict__ w1_0, const float* __restrict__ bb1_0,
    const float* __restrict__ w2_0, const float* __restrict__ bb2_0,
    const float* __restrict__ w3_0,
    const float* __restrict__ w1_1, const float* __restrict__ bb1_1,
    const float* __restrict__ w2_1, const float* __restrict__ bb2_1,
    const float* __restrict__ w3_1,
    const float* __restrict__ w1_2, const float* __restrict__ bb1_2,
    const float* __restrict__ w2_2, const float* __restrict__ bb2_2,
    const float* __restrict__ w3_2,
    const float* __restrict__ w1_3, const float* __restrict__ bb1_3,
    const float* __restrict__ w2_3, const float* __restrict__ bb2_3,
    const float* __restrict__ w3_3,
    float* __restrict__ out)
{
  __shared__ __align__(16) char smem[SMEM_BYTES];
  int*            ssrc = (int*)(smem + 0);
  int*            sdst = (int*)(smem + 64);
  unsigned short* h2hi = (unsigned short*)(smem + 128);    // [4][16][32]
  unsigned short* h2lo = (unsigned short*)(smem + 4224);   // [4][16][32]
  float*          ts0  = (float*)(smem + 8320);            // [16][20]
  float*          ts1  = (float*)(smem + 9600);            // [16][52]
  float*          ts2  = (float*)(smem + 12928);           // [16][20]
  float*          ts3  = (float*)(smem + 14208);           // [16][148]
  float*          rws  = (float*)(smem + 23680);           // [16][388]
  float*          eis  = (float*)(smem + 23680);           // [16][2]  (EARLY)
  float*          h1s  = (float*)(smem + 23808);           // [4][16][33]
  float*          sf0  = (float*)(smem + 32256);           // [16][16]
  float*          sf1  = (float*)(smem + 33280);           // [16][48]
  float*          sb00 = (float*)(smem + 36352);           // [16]
  float*          sb01 = (float*)(smem + 36416);           // [16][3]
  float*          sb10 = (float*)(smem + 36608);           // [16][3]
  float*          sb11 = (float*)(smem + 36800);           // [16][27]

  const int t    = threadIdx.x;
  const int wid  = t >> 6;
  const int lane = t & 63;
  const int x    = lane & 15;     // MFMA: A-row(edge) / B-col / D-col
  const int g    = lane >> 4;     // MFMA: k-chunk / D row-chunk
  const int ce   = t >> 4;        // contraction: edge
  const int cco  = t & 15;        // contraction: c_out
  const int e0   = blockIdx.x * TE;

  // ---- P0: stage per-edge scalars ----
  for (int i = t; i < TE * 2; i += BLOCK) eis[i] = edge_inv[e0 * 2 + i];
  if (t < TE) { ssrc[t] = src[e0 + t]; sdst[t] = dst[e0 + t]; sb00[t] = b00[e0 + t]; }
  for (int i = t; i < TE * 3; i += BLOCK) {
    sb01[i] = b01[e0 * 3 + i];
    sb10[i] = b10[e0 * 3 + i];
  }
  for (int i = t; i < TE * 27; i += BLOCK) sb11[i] = b11[e0 * 27 + i];
  __syncthreads();

  // ---- P1a: h1 = relu(edge_inv @ W1 + b1) -> fp32 LDS ----
  {
    const int combo = t & 127, p = combo >> 5, m = combo & 31, eb = (t >> 7) * 8;
    const float* w1p = p == 0 ? w1_0 : p == 1 ? w1_1 : p == 2 ? w1_2 : w1_3;
    const float* b1p = p == 0 ? bb1_0 : p == 1 ? bb1_1 : p == 2 ? bb1_2 : bb1_3;
    const float wa = w1p[m], wb = w1p[32 + m], bv = b1p[m];
    #pragma unroll
    for (int ee = 0; ee < 8; ++ee) {
      const int ei = eb + ee;
      const float v = fmaf(eis[ei * 2], wa, fmaf(eis[ei * 2 + 1], wb, bv));
      h1s[p * 528 + ei * 33 + m] = v > 0.f ? v : 0.f;
    }
  }
  // ---- P2a: gather source-node features ----
  for (int i = t; i < TE * 16; i += BLOCK) {
    const int ei = i >> 4;
    sf0[ei * 16 + (i & 15)] = feat0[ssrc[ei] * 16 + (i & 15)];
  }
  for (int i = t; i < TE * 48; i += BLOCK) {
    const int ei = i / 48;
    sf1[ei * 48 + i % 48] = feat1[ssrc[ei] * 48 + (i % 48)];
  }
  __syncthreads();

  // ---- P1b: h2 = relu(h1 @ W2 + b2), exact fp32; truncation hi/lo to LDS ----
  {
    const int p = wid;
    const float* w2p = p == 0 ? w2_0 : p == 1 ? w2_1 : p == 2 ? w2_2 : w2_3;
    const float* b2p = p == 0 ? bb2_0 : p == 1 ? bb2_1 : p == 2 ? bb2_2 : bb2_3;
    float acc[8];                 // lane (x,g): edge x, m = 8g..8g+7
    #pragma unroll
    for (int mm = 0; mm < 8; ++mm) acc[mm] = b2p[8 * g + mm];
    #pragma unroll
    for (int i = 0; i < 32; ++i) {
      const float hv = h1s[p * 528 + x * 33 + i];
      const f32x4 wA = *(const f32x4*)(w2p + i * 32 + 8 * g);
      const f32x4 wB = *(const f32x4*)(w2p + i * 32 + 8 * g + 4);
      acc[0] = fmaf(hv, wA[0], acc[0]); acc[1] = fmaf(hv, wA[1], acc[1]);
      acc[2] = fmaf(hv, wA[2], acc[2]); acc[3] = fmaf(hv, wA[3], acc[3]);
      acc[4] = fmaf(hv, wB[0], acc[4]); acc[5] = fmaf(hv, wB[1], acc[5]);
      acc[6] = fmaf(hv, wB[2], acc[6]); acc[7] = fmaf(hv, wB[3], acc[7]);
    }
    short8 hv8, lv8;
    #pragma unroll
    for (int mm = 0; mm < 8; ++mm) {
      const float v = acc[mm] > 0.f ? acc[mm] : 0.f;
      const unsigned u = __builtin_bit_cast(unsigned, v);
      const float hi = __builtin_bit_cast(float, u & 0xFFFF0000u);
      hv8[mm] = (short)(u >> 16);
      lv8[mm] = (short)f2b(v - hi);
    }
    *(short8*)(h2hi + p * 512 + x * 32 + 8 * g) = hv8;
    *(short8*)(h2lo + p * 512 + x * 32 + 8 * g) = lv8;
  }
  // ---- P2b: tmp tensors (fp32) ----
  for (int i = t; i < TE * 16; i += BLOCK) {
    const int ei = i >> 4, k = i & 15;
    ts0[ei * 20 + k] = sf0[ei * 16 + k] * sb00[ei];
    float a = 0.f;
    #pragma unroll
    for (int ii = 0; ii < 3; ++ii)
      a = fmaf(sf1[ei * 48 + k * 3 + ii], sb10[ei * 3 + ii], a);
    ts2[ei * 20 + k] = a;
  }
  for (int i = t; i < TE * 48; i += BLOCK) {
    const int ei = i / 48, r = i % 48, k = r / 3, dd = r % 3;
    ts1[ei * 52 + k * 3 + dd] = sf0[ei * 16 + k] * sb01[ei * 3 + dd];
  }
  for (int i = t; i < TE * 144; i += BLOCK) {
    const int ei = i / 144, r = i % 144, k = r / 3, dd = r % 3, ci = k / 3, f = k % 3;
    float a = 0.f;
    #pragma unroll
    for (int ii = 0; ii < 3; ++ii)
      a = fmaf(sf1[ei * 48 + ci * 3 + ii], sb11[ei * 27 + ii * 9 + f * 3 + dd], a);
    ts3[ei * 148 + k * 3 + dd] = a;
  }
  __syncthreads();   // EARLY region dead from here; rws may be written

  float o0 = 0.f, o1 = 0.f, o2 = 0.f, o3 = 0.f;  // thread (ce, cco)

  // ===== Pair 0: K=16, DO=1 (slot 0) =====
  {
    const short8 Ah = *(const short8*)(h2hi + 0 * 512 + x * 32 + 8 * g);
    const short8 Al = *(const short8*)(h2lo + 0 * 512 + x * 32 + 8 * g);
    #pragma unroll
    for (int i = 0; i < 4; ++i) {
      const int c0 = (wid * 4 + i) * 16;
      const float* bp = w3_0 + (8 * g) * 256 + c0 + x;
      short8 Bh, Bl;
      #pragma unroll
      for (int j = 0; j < 8; ++j) {
        const float v = bp[j * 256];
        const unsigned u = __builtin_bit_cast(unsigned, v);
        Bh[j] = (short)(u >> 16);
        Bl[j] = (short)f2b(v - __builtin_bit_cast(float, u & 0xFFFF0000u));
      }
      f32x4 d = {0.f, 0.f, 0.f, 0.f};
      d = __builtin_amdgcn_mfma_f32_16x16x32_bf16(Ah, Bl, d, 0, 0, 0);
      d = __builtin_amdgcn_mfma_f32_16x16x32_bf16(Al, Bh, d, 0, 0, 0);
      d = __builtin_amdgcn_mfma_f32_16x16x32_bf16(Ah, Bh, d, 0, 0, 0);
      #pragma unroll
      for (int r = 0; r < 4; ++r) rws[(4 * g + r) * RWS_STRIDE + c0 + x] = d[r];
    }
  }
  __syncthreads();
  #pragma unroll
  for (int k = 0; k < 16; ++k)
    o0 = fmaf(rws[ce * RWS_STRIDE + cco * 16 + k], ts0[ce * 20 + k], o0);
  __syncthreads();

  // ===== Pair 1: K=16, DO=3 (slots 1..3) =====
  {
    const short8 Ah = *(const short8*)(h2hi + 1 * 512 + x * 32 + 8 * g);
    const short8 Al = *(const short8*)(h2lo + 1 * 512 + x * 32 + 8 * g);
    #pragma unroll
    for (int i = 0; i < 4; ++i) {
      const int c0 = (wid * 4 + i) * 16;
      const float* bp = w3_1 + (8 * g) * 256 + c0 + x;
      short8 Bh, Bl;
      #pragma unroll
      for (int j = 0; j < 8; ++j) {
        const float v = bp[j * 256];
        const unsigned u = __builtin_bit_cast(unsigned, v);
        Bh[j] = (short)(u >> 16);
        Bl[j] = (short)f2b(v - __builtin_bit_cast(float, u & 0xFFFF0000u));
      }
      f32x4 d = {0.f, 0.f, 0.f, 0.f};
      d = __builtin_amdgcn_mfma_f32_16x16x32_bf16(Ah, Bl, d, 0, 0, 0);
      d = __builtin_amdgcn_mfma_f32_16x16x32_bf16(Al, Bh, d, 0, 0, 0);
      d = __builtin_amdgcn_mfma_f32_16x16x32_bf16(Ah, Bh, d, 0, 0, 0);
      #pragma unroll
      for (int r = 0; r < 4; ++r) rws[(4 * g + r) * RWS_STRIDE + c0 + x] = d[r];
    }
  }
  __syncthreads();
  #pragma unroll
  for (int k = 0; k < 16; ++k) {
    const float rv = rws[ce * RWS_STRIDE + cco * 16 + k];
    o1 = fmaf(rv, ts1[ce * 52 + k * 3 + 0], o1);
    o2 = fmaf(rv, ts1[ce * 52 + k * 3 + 1], o2);
    o3 = fmaf(rv, ts1[ce * 52 + k * 3 + 2], o3);
  }
  __syncthreads();

  // ===== Pair 2: K=16, DO=1 (slot 0) =====
  {
    const short8 Ah = *(const short8*)(h2hi + 2 * 512 + x * 32 + 8 * g);
    const short8 Al = *(const short8*)(h2lo + 2 * 512 + x * 32 + 8 * g);
    #pragma unroll
    for (int i = 0; i < 4; ++i) {
      const int c0 = (wid * 4 + i) * 16;
      const float* bp = w3_2 + (8 * g) * 256 + c0 + x;
      short8 Bh, Bl;
      #pragma unroll
      for (int j = 0; j < 8; ++j) {
        const float v = bp[j * 256];
        const unsigned u = __builtin_bit_cast(unsigned, v);
        Bh[j] = (short)(u >> 16);
        Bl[j] = (short)f2b(v - __builtin_bit_cast(float, u & 0xFFFF0000u));
      }
      f32x4 d = {0.f, 0.f, 0.f, 0.f};
      d = __builtin_amdgcn_mfma_f32_16x16x32_bf16(Ah, Bl, d, 0, 0, 0);
      d = __builtin_amdgcn_mfma_f32_16x16x32_bf16(Al, Bh, d, 0, 0, 0);
      d = __builtin_amdgcn_mfma_f32_16x16x32_bf16(Ah, Bh, d, 0, 0, 0);
      #pragma unroll
      for (int r = 0; r < 4; ++r) rws[(4 * g + r) * RWS_STRIDE + c0 + x] = d[r];
    }
  }
  __syncthreads();
  #pragma unroll
  for (int k = 0; k < 16; ++k)
    o0 = fmaf(rws[ce * RWS_STRIDE + cco * 16 + k], ts2[ce * 20 + k], o0);
  __syncthreads();

  // ===== Pair 3: K=48, DO=3 (slots 1..3), two column-halves =====
  {
    const short8 Ah = *(const short8*)(h2hi + 3 * 512 + x * 32 + 8 * g);
    const short8 Al = *(const short8*)(h2lo + 3 * 512 + x * 32 + 8 * g);
    #pragma unroll
    for (int h = 0; h < 2; ++h) {
      #pragma unroll
      for (int i = 0; i < 6; ++i) {
        const int tl = wid * 6 + i;          // 0..23
        const int col_ = tl / 3, kc = tl % 3;
        const int cg0 = (h * 8 + col_) * 48 + kc * 16;   // global col base
        const int cl0 = col_ * 48 + kc * 16;             // local col base
        const float* bp = w3_3 + (8 * g) * 768 + cg0 + x;
        short8 Bh, Bl;
        #pragma unroll
        for (int j = 0; j < 8; ++j) {
          const float v = bp[j * 768];
          const unsigned u = __builtin_bit_cast(unsigned, v);
          Bh[j] = (short)(u >> 16);
          Bl[j] = (short)f2b(v - __builtin_bit_cast(float, u & 0xFFFF0000u));
        }
        f32x4 d = {0.f, 0.f, 0.f, 0.f};
        d = __builtin_amdgcn_mfma_f32_16x16x32_bf16(Ah, Bl, d, 0, 0, 0);
        d = __builtin_amdgcn_mfma_f32_16x16x32_bf16(Al, Bh, d, 0, 0, 0);
        d = __builtin_amdgcn_mfma_f32_16x16x32_bf16(Ah, Bh, d, 0, 0, 0);
        #pragma unroll
        for (int r = 0; r < 4; ++r) rws[(4 * g + r) * RWS_STRIDE + cl0 + x] = d[r];
      }
      __syncthreads();
      if ((cco >> 3) == h) {
        const int col_ = cco & 7;
        for (int k = 0; k < 48; ++k) {
          const float rv = rws[ce * RWS_STRIDE + col_ * 48 + k];
          o1 = fmaf(rv, ts3[ce * 148 + k * 3 + 0], o1);
          o2 = fmaf(rv, ts3[ce * 148 + k * 3 + 1], o2);
          o3 = fmaf(rv, ts3[ce * 148 + k * 3 + 2], o3);
        }
      }
      __syncthreads();
    }
  }

  // ---- P4: scatter into out[N][16][4] ----
  {
    float* op = out + (size_t)sdst[ce] * 64 + cco * 4;
    atomicAdd(op + 0, o0);
    atomicAdd(op + 1, o1);
    atomicAdd(op + 2, o2);
    atomicAdd(op + 3, o3);
  }
}

extern "C" void kernel_launch(void* const* d_in, const int* in_sizes, int n_in,
                              void* d_out, int out_size, void* d_ws, size_t ws_size,
                              hipStream_t stream)
{
  const float* feat0    = (const float*)d_in[0];
  const float* feat1    = (const float*)d_in[1];
  const float* edge_inv = (const float*)d_in[2];
  const int*   src      = (const int*)d_in[3];
  const int*   dst      = (const int*)d_in[4];
  const float* b00      = (const float*)d_in[5];
  const float* b01      = (const float*)d_in[6];
  const float* b10      = (const float*)d_in[7];
  const float* b11      = (const float*)d_in[8];
  const float* w1[4]; const float* bb1[4]; const float* w2[4]; const float* bb2[4]; const float* w3[4];
  for (int p = 0; p < 4; ++p) {   // dict order: 00, 01, 10, 11
    w1[p]  = (const float*)d_in[9 + 5 * p + 0];
    bb1[p] = (const float*)d_in[9 + 5 * p + 1];
    w2[p]  = (const float*)d_in[9 + 5 * p + 2];
    bb2[p] = (const float*)d_in[9 + 5 * p + 3];
    w3[p]  = (const float*)d_in[9 + 5 * p + 4];
  }
  float* out = (float*)d_out;
  const int E = in_sizes[3];   // 160000

  hipMemsetAsync(d_out, 0, (size_t)out_size * sizeof(float), stream);

  hipLaunchKernelGGL(conv_se3_kernel, dim3(E / TE), dim3(BLOCK), 0, stream,
      feat0, feat1, edge_inv, src, dst, b00, b01, b10, b11,
      w1[0], bb1[0], w2[0], bb2[0], w3[0],
      w1[1], bb1[1], w2[1], bb2[1], w3[1],
      w1[2], bb1[2], w2[2], bb2[2], w3[2],
      w1[3], bb1[3], w2[3], bb2[3], w3[3],
      out);
}

// Round 8
// 431.347 us; speedup vs baseline: 2.1133x; 1.0125x over previous
//
#include <hip/hip_runtime.h>
#include <hip/hip_bf16.h>

// ConvSE3 fused — standard-orientation MFMA (r7-verified) + ws-precomputed
// split-bf16 W3 fragments + 4-blocks/CU LDS budget.
// E=160000, N=10000, C=16, MID=32, TE=16 edges/block.
// Pairs: p0="00"(K=16,DO=1,slot0) p1="01"(K=16,DO=3,slot1..3)
//        p2="10"(K=16,DO=1,slot0) p3="11"(K=48,DO=3,slot1..3)
// rw col = c_out*K + k, k = c_in*nf + f.
// GEMM: D[edge][w3col] = sum_m h2[edge][m] * w3[m][col]   (A=h2, B=w3)
//   A-frag: lane&15 = edge row, k = 8*(lane>>4)+j ; B-frag: lane&15 = col.
//   D: col = lane&15, row = 4*(lane>>4)+reg  [m89-verified]
// Split-bf16: v = hi(truncate) + lo(rtn residual); D += Ah*Bl + Al*Bh + Ah*Bh.
// ws layout: 96 tiles x 1024 ushort: [tile][hi:512 | lo:512], element = lane*8+j.
//   tile id: p0: 0..15 (co), p1: 16..31, p2: 32..47, p3: 48 + co*3 + kc.

#define BLOCK 256
constexpr int TE = 16;
constexpr int N_TILES = 96;
constexpr int PREP_THREADS = N_TILES * 512;              // 49152
constexpr size_t PREP_BYTES = (size_t)N_TILES * 1024 * 2; // 196608

typedef __attribute__((ext_vector_type(8))) short short8;
typedef __attribute__((ext_vector_type(4))) float f32x4;

__device__ __forceinline__ unsigned short f2b(float x) {
  return __builtin_bit_cast(unsigned short, __float2bfloat16(x));
}

__global__ __launch_bounds__(256) void prep_kernel(
    const float* __restrict__ w3_0, const float* __restrict__ w3_1,
    const float* __restrict__ w3_2, const float* __restrict__ w3_3,
    unsigned short* __restrict__ ws)
{
  const int gid = blockIdx.x * 256 + threadIdx.x;
  if (gid >= PREP_THREADS) return;
  const int tid = gid >> 9;            // tile 0..95
  const int l   = gid & 511;           // element within tile
  const int lane = l >> 3, j = l & 7;
  const int x = lane & 15, g = lane >> 4;
  const int m = 8 * g + j;
  const float* w3; int NC, c0;
  if (tid < 16)      { w3 = w3_0; NC = 256; c0 = tid * 16; }
  else if (tid < 32) { w3 = w3_1; NC = 256; c0 = (tid - 16) * 16; }
  else if (tid < 48) { w3 = w3_2; NC = 256; c0 = (tid - 32) * 16; }
  else { const int t3 = tid - 48, co = t3 / 3, kc = t3 % 3;
         w3 = w3_3; NC = 768; c0 = co * 48 + kc * 16; }
  const float v = w3[m * NC + c0 + x];
  const unsigned u = __builtin_bit_cast(unsigned, v);
  ws[tid * 1024 + l] = (unsigned short)(u >> 16);
  ws[tid * 1024 + 512 + l] =
      f2b(v - __builtin_bit_cast(float, u & 0xFFFF0000u));
}

// ---- LDS pool (bytes). PERS lives whole kernel; EARLY aliases rws. ----
// PERS: ssrc@0(64) sdst@64(64) h2hi@128(4096) h2lo@4224(4096)
//       ts0@8320(1280) ts1@9600(3328) ts2@12928(1280) ts3@14208(9344)
// LATE: rws@23552 float[16][260] (16640) -> total 40192 (4 blocks/CU)
// EARLY(alias rws): eis@23552(128) h1s@23680(8448) sf0@32128(1024)
//       sf1@33152(3072) sb00@36224(64) sb01@36288(192) sb10@36480(192)
//       sb11@36672(1728) -> ends 38400 <= 40192
constexpr int SMEM_BYTES = 40192;
constexpr int RWS_STRIDE = 260;
constexpr int TS3_STRIDE = 146;

template<bool USE_WS, int NC>
__device__ __forceinline__ void get_bfrag(
    const unsigned short* __restrict__ ws, int tid,
    const float* __restrict__ w3, int c0, int x, int g, int lane,
    short8& Bh, short8& Bl)
{
  if constexpr (USE_WS) {
    const unsigned short* tb = ws + tid * 1024 + lane * 8;
    Bh = *(const short8*)tb;
    Bl = *(const short8*)(tb + 512);
  } else {
    const float* bp = w3 + (8 * g) * NC + c0 + x;
    #pragma unroll
    for (int j = 0; j < 8; ++j) {
      const float v = bp[j * NC];
      const unsigned u = __builtin_bit_cast(unsigned, v);
      Bh[j] = (short)(u >> 16);
      Bl[j] = (short)f2b(v - __builtin_bit_cast(float, u & 0xFFFF0000u));
    }
  }
}

__device__ __forceinline__ f32x4 mfma3(short8 Ah, short8 Al, short8 Bh, short8 Bl) {
  f32x4 d = {0.f, 0.f, 0.f, 0.f};
  d = __builtin_amdgcn_mfma_f32_16x16x32_bf16(Ah, Bl, d, 0, 0, 0);
  d = __builtin_amdgcn_mfma_f32_16x16x32_bf16(Al, Bh, d, 0, 0, 0);
  d = __builtin_amdgcn_mfma_f32_16x16x32_bf16(Ah, Bh, d, 0, 0, 0);
  return d;
}

template<bool USE_WS>
__global__ __launch_bounds__(BLOCK) void conv_se3_kernel(
    const float* __restrict__ feat0,
    const float* __restrict__ feat1,
    const float* __restrict__ edge_inv,
    const int*   __restrict__ src,
    const int*   __restrict__ dst,
    const float* __restrict__ b00,
    const float* __restrict__ b01,
    const float* __restrict__ b10,
    const float* __restrict__ b11,
    const float* __restrict__ w1_0, const float* __restrict__ bb1_0,
    const float* __restrict__ w2_0, const float* __restrict__ bb2_0,
    const float* __restrict__ w3_0,
    const float* __restrict__ w1_1, const float* __restrict__ bb1_1,
    const float* __restrict__ w2_1, const float* __restrict__ bb2_1,
    const float* __restrict__ w3_1,
    const float* __restrict__ w1_2, const float* __restrict__ bb1_2,
    const float* __restrict__ w2_2, const float* __restrict__ bb2_2,
    const float* __restrict__ w3_2,
    const float* __restrict__ w1_3, const float* __restrict__ bb1_3,
    const float* __restrict__ w2_3, const float* __restrict__ bb2_3,
    const float* __restrict__ w3_3,
    const unsigned short* __restrict__ ws,
    float* __restrict__ out)
{
  __shared__ __align__(16) char smem[SMEM_BYTES];
  int*            ssrc = (int*)(smem + 0);
  int*            sdst = (int*)(smem + 64);
  unsigned short* h2hi = (unsigned short*)(smem + 128);    // [4][16][32]
  unsigned short* h2lo = (unsigned short*)(smem + 4224);   // [4][16][32]
  float*          ts0  = (float*)(smem + 8320);            // [16][20]
  float*          ts1  = (float*)(smem + 9600);            // [16][52]
  float*          ts2  = (float*)(smem + 12928);           // [16][20]
  float*          ts3  = (float*)(smem + 14208);           // [16][146]
  float*          rws  = (float*)(smem + 23552);           // [16][260]
  float*          eis  = (float*)(smem + 23552);           // EARLY aliases below
  float*          h1s  = (float*)(smem + 23680);           // [4][16][33]
  float*          sf0  = (float*)(smem + 32128);           // [16][16]
  float*          sf1  = (float*)(smem + 33152);           // [16][48]
  float*          sb00 = (float*)(smem + 36224);           // [16]
  float*          sb01 = (float*)(smem + 36288);           // [16][3]
  float*          sb10 = (float*)(smem + 36480);           // [16][3]
  float*          sb11 = (float*)(smem + 36672);           // [16][27]

  const int t    = threadIdx.x;
  const int wid  = t >> 6;
  const int lane = t & 63;
  const int x    = lane & 15;     // MFMA: A-row(edge) / B-col / D-col
  const int g    = lane >> 4;     // MFMA: k-chunk / D row-chunk
  const int ce   = t >> 4;        // contraction: edge
  const int cco  = t & 15;        // contraction: c_out
  const int e0   = blockIdx.x * TE;

  // ---- P0: stage per-edge scalars ----
  for (int i = t; i < TE * 2; i += BLOCK) eis[i] = edge_inv[e0 * 2 + i];
  if (t < TE) { ssrc[t] = src[e0 + t]; sdst[t] = dst[e0 + t]; sb00[t] = b00[e0 + t]; }
  for (int i = t; i < TE * 3; i += BLOCK) {
    sb01[i] = b01[e0 * 3 + i];
    sb10[i] = b10[e0 * 3 + i];
  }
  for (int i = t; i < TE * 27; i += BLOCK) sb11[i] = b11[e0 * 27 + i];
  __syncthreads();

  // ---- P1a: h1 = relu(edge_inv @ W1 + b1) -> fp32 LDS ----
  {
    const int combo = t & 127, p = combo >> 5, m = combo & 31, eb = (t >> 7) * 8;
    const float* w1p = p == 0 ? w1_0 : p == 1 ? w1_1 : p == 2 ? w1_2 : w1_3;
    const float* b1p = p == 0 ? bb1_0 : p == 1 ? bb1_1 : p == 2 ? bb1_2 : bb1_3;
    const float wa = w1p[m], wb = w1p[32 + m], bv = b1p[m];
    #pragma unroll
    for (int ee = 0; ee < 8; ++ee) {
      const int ei = eb + ee;
      const float v = fmaf(eis[ei * 2], wa, fmaf(eis[ei * 2 + 1], wb, bv));
      h1s[p * 528 + ei * 33 + m] = v > 0.f ? v : 0.f;
    }
  }
  // ---- P2a: gather source-node features ----
  for (int i = t; i < TE * 16; i += BLOCK) {
    const int ei = i >> 4;
    sf0[ei * 16 + (i & 15)] = feat0[ssrc[ei] * 16 + (i & 15)];
  }
  for (int i = t; i < TE * 48; i += BLOCK) {
    const int ei = i / 48;
    sf1[ei * 48 + i % 48] = feat1[ssrc[ei] * 48 + (i % 48)];
  }
  __syncthreads();

  // ---- P1b: h2 = relu(h1 @ W2 + b2), exact fp32; truncation hi/lo to LDS ----
  {
    const int p = wid;
    const float* w2p = p == 0 ? w2_0 : p == 1 ? w2_1 : p == 2 ? w2_2 : w2_3;
    const float* b2p = p == 0 ? bb2_0 : p == 1 ? bb2_1 : p == 2 ? bb2_2 : bb2_3;
    float acc[8];                 // lane (x,g): edge x, m = 8g..8g+7
    #pragma unroll
    for (int mm = 0; mm < 8; ++mm) acc[mm] = b2p[8 * g + mm];
    #pragma unroll
    for (int i = 0; i < 32; ++i) {
      const float hv = h1s[p * 528 + x * 33 + i];
      const f32x4 wA = *(const f32x4*)(w2p + i * 32 + 8 * g);
      const f32x4 wB = *(const f32x4*)(w2p + i * 32 + 8 * g + 4);
      acc[0] = fmaf(hv, wA[0], acc[0]); acc[1] = fmaf(hv, wA[1], acc[1]);
      acc[2] = fmaf(hv, wA[2], acc[2]); acc[3] = fmaf(hv, wA[3], acc[3]);
      acc[4] = fmaf(hv, wB[0], acc[4]); acc[5] = fmaf(hv, wB[1], acc[5]);
      acc[6] = fmaf(hv, wB[2], acc[6]); acc[7] = fmaf(hv, wB[3], acc[7]);
    }
    short8 hv8, lv8;
    #pragma unroll
    for (int mm = 0; mm < 8; ++mm) {
      const float v = acc[mm] > 0.f ? acc[mm] : 0.f;
      const unsigned u = __builtin_bit_cast(unsigned, v);
      const float hi = __builtin_bit_cast(float, u & 0xFFFF0000u);
      hv8[mm] = (short)(u >> 16);
      lv8[mm] = (short)f2b(v - hi);
    }
    *(short8*)(h2hi + p * 512 + x * 32 + 8 * g) = hv8;
    *(short8*)(h2lo + p * 512 + x * 32 + 8 * g) = lv8;
  }
  // ---- P2b: tmp tensors (fp32) ----
  for (int i = t; i < TE * 16; i += BLOCK) {
    const int ei = i >> 4, k = i & 15;
    ts0[ei * 20 + k] = sf0[ei * 16 + k] * sb00[ei];
    float a = 0.f;
    #pragma unroll
    for (int ii = 0; ii < 3; ++ii)
      a = fmaf(sf1[ei * 48 + k * 3 + ii], sb10[ei * 3 + ii], a);
    ts2[ei * 20 + k] = a;
  }
  for (int i = t; i < TE * 48; i += BLOCK) {
    const int ei = i / 48, r = i % 48, k = r / 3, dd = r % 3;
    ts1[ei * 52 + k * 3 + dd] = sf0[ei * 16 + k] * sb01[ei * 3 + dd];
  }
  for (int i = t; i < TE * 144; i += BLOCK) {
    const int ei = i / 144, r = i % 144, k = r / 3, dd = r % 3, ci = k / 3, f = k % 3;
    float a = 0.f;
    #pragma unroll
    for (int ii = 0; ii < 3; ++ii)
      a = fmaf(sf1[ei * 48 + ci * 3 + ii], sb11[ei * 27 + ii * 9 + f * 3 + dd], a);
    ts3[ei * TS3_STRIDE + k * 3 + dd] = a;
  }
  __syncthreads();   // EARLY region dead from here; rws may be written

  float o0 = 0.f, o1 = 0.f, o2 = 0.f, o3 = 0.f;  // thread (ce, cco)

  // ===== Pairs 0..2: K=16 =====
  #pragma unroll
  for (int p = 0; p < 3; ++p) {
    const short8 Ah = *(const short8*)(h2hi + p * 512 + x * 32 + 8 * g);
    const short8 Al = *(const short8*)(h2lo + p * 512 + x * 32 + 8 * g);
    const float* w3p = p == 0 ? w3_0 : p == 1 ? w3_1 : w3_2;
    #pragma unroll
    for (int i = 0; i < 4; ++i) {
      const int co = wid * 4 + i;
      const int c0 = co * 16;
      short8 Bh, Bl;
      get_bfrag<USE_WS, 256>(ws, p * 16 + co, w3p, c0, x, g, lane, Bh, Bl);
      const f32x4 d = mfma3(Ah, Al, Bh, Bl);
      #pragma unroll
      for (int r = 0; r < 4; ++r) rws[(4 * g + r) * RWS_STRIDE + c0 + x] = d[r];
    }
    __syncthreads();
    if (p == 0) {
      #pragma unroll
      for (int k = 0; k < 16; ++k)
        o0 = fmaf(rws[ce * RWS_STRIDE + cco * 16 + k], ts0[ce * 20 + k], o0);
    } else if (p == 1) {
      #pragma unroll
      for (int k = 0; k < 16; ++k) {
        const float rv = rws[ce * RWS_STRIDE + cco * 16 + k];
        o1 = fmaf(rv, ts1[ce * 52 + k * 3 + 0], o1);
        o2 = fmaf(rv, ts1[ce * 52 + k * 3 + 1], o2);
        o3 = fmaf(rv, ts1[ce * 52 + k * 3 + 2], o3);
      }
    } else {
      #pragma unroll
      for (int k = 0; k < 16; ++k)
        o0 = fmaf(rws[ce * RWS_STRIDE + cco * 16 + k], ts2[ce * 20 + k], o0);
    }
    __syncthreads();
  }

  // ===== Pair 3: K=48, four column-quarters (4 co each) =====
  {
    const short8 Ah = *(const short8*)(h2hi + 3 * 512 + x * 32 + 8 * g);
    const short8 Al = *(const short8*)(h2lo + 3 * 512 + x * 32 + 8 * g);
    #pragma unroll
    for (int q = 0; q < 4; ++q) {
      #pragma unroll
      for (int i = 0; i < 3; ++i) {
        const int tl = wid * 3 + i;            // 0..11
        const int col_l = tl / 3, kc = tl % 3; // col_l 0..3
        const int co = 4 * q + col_l;
        const int cg0 = co * 48 + kc * 16;
        const int cl0 = col_l * 48 + kc * 16;  // local cols 0..191
        short8 Bh, Bl;
        get_bfrag<USE_WS, 768>(ws, 48 + co * 3 + kc, w3_3, cg0, x, g, lane, Bh, Bl);
        const f32x4 d = mfma3(Ah, Al, Bh, Bl);
        #pragma unroll
        for (int r = 0; r < 4; ++r) rws[(4 * g + r) * RWS_STRIDE + cl0 + x] = d[r];
      }
      __syncthreads();
      if ((cco >> 2) == q) {
        const int col_l = cco & 3;
        for (int k = 0; k < 48; ++k) {
          const float rv = rws[ce * RWS_STRIDE + col_l * 48 + k];
          o1 = fmaf(rv, ts3[ce * TS3_STRIDE + k * 3 + 0], o1);
          o2 = fmaf(rv, ts3[ce * TS3_STRIDE + k * 3 + 1], o2);
          o3 = fmaf(rv, ts3[ce * TS3_STRIDE + k * 3 + 2], o3);
        }
      }
      __syncthreads();
    }
  }

  // ---- P4: scatter into out[N][16][4] ----
  {
    float* op = out + (size_t)sdst[ce] * 64 + cco * 4;
    atomicAdd(op + 0, o0);
    atomicAdd(op + 1, o1);
    atomicAdd(op + 2, o2);
    atomicAdd(op + 3, o3);
  }
}

extern "C" void kernel_launch(void* const* d_in, const int* in_sizes, int n_in,
                              void* d_out, int out_size, void* d_ws, size_t ws_size,
                              hipStream_t stream)
{
  const float* feat0    = (const float*)d_in[0];
  const float* feat1    = (const float*)d_in[1];
  const float* edge_inv = (const float*)d_in[2];
  const int*   src      = (const int*)d_in[3];
  const int*   dst      = (const int*)d_in[4];
  const float* b00      = (const float*)d_in[5];
  const float* b01      = (const float*)d_in[6];
  const float* b10      = (const float*)d_in[7];
  const float* b11      = (const float*)d_in[8];
  const float* w1[4]; const float* bb1[4]; const float* w2[4]; const float* bb2[4]; const float* w3[4];
  for (int p = 0; p < 4; ++p) {   // dict order: 00, 01, 10, 11
    w1[p]  = (const float*)d_in[9 + 5 * p + 0];
    bb1[p] = (const float*)d_in[9 + 5 * p + 1];
    w2[p]  = (const float*)d_in[9 + 5 * p + 2];
    bb2[p] = (const float*)d_in[9 + 5 * p + 3];
    w3[p]  = (const float*)d_in[9 + 5 * p + 4];
  }
  float* out = (float*)d_out;
  unsigned short* wsp = (unsigned short*)d_ws;
  const int E = in_sizes[3];   // 160000

  hipMemsetAsync(d_out, 0, (size_t)out_size * sizeof(float), stream);

  const bool use_ws = (ws_size >= PREP_BYTES);   // constant across calls
  if (use_ws) {
    hipLaunchKernelGGL(prep_kernel, dim3((PREP_THREADS + 255) / 256), dim3(256),
                       0, stream, w3[0], w3[1], w3[2], w3[3], wsp);
    hipLaunchKernelGGL((conv_se3_kernel<true>), dim3(E / TE), dim3(BLOCK), 0, stream,
        feat0, feat1, edge_inv, src, dst, b00, b01, b10, b11,
        w1[0], bb1[0], w2[0], bb2[0], w3[0],
        w1[1], bb1[1], w2[1], bb2[1], w3[1],
        w1[2], bb1[2], w2[2], bb2[2], w3[2],
        w1[3], bb1[3], w2[3], bb2[3], w3[3],
        wsp, out);
  } else {
    hipLaunchKernelGGL((conv_se3_kernel<false>), dim3(E / TE), dim3(BLOCK), 0, stream,
        feat0, feat1, edge_inv, src, dst, b00, b01, b10, b11,
        w1[0], bb1[0], w2[0], bb2[0], w3[0],
        w1[1], bb1[1], w2[1], bb2[1], w3[1],
        w1[2], bb1[2], w2[2], bb2[2], w3[2],
        w1[3], bb1[3], w2[3], bb2[3], w3[3],
        wsp, out);
  }
}

// Round 9
// 367.954 us; speedup vs baseline: 2.4773x; 1.1723x over previous
//
#include <hip/hip_runtime.h>
#include <hip/hip_bf16.h>

// ConvSE3 fused — r7-verified MFMA orientation + in-register epilogue:
//   D-fragment contraction with DPP rotate-reduce (VALU pipe, no LDS round-trip)
//   + r1-style coalesced row atomics via small oacc transpose buffer.
// E=160000, N=10000, C=16, MID=32, TE=16 edges/block.
// Pairs: p0="00"(K=16,slot0) p1="01"(K=16,slots1-3) p2="10"(K=16,slot0)
//        p3="11"(K=48,slots1-3).  rw col = c_out*K + k, k = c_in*nf + f.
// GEMM: D[edge][w3col] = sum_m h2[edge][m] * w3[m][col]  (A=h2, B=w3)
//   A-frag lane&15 = edge row; B-frag lane&15 = col; k = 8*(lane>>4)+j.
//   D: col = lane&15 (k within tile), row = 4*(lane>>4)+reg (edge). [m89-verified]
// Wave wid owns output cols co = 4*wid..4*wid+3 (pair3: co = 4*wid+q per quarter)
//   -> lane (x,g) accumulates out[e=4g+(x&3)][co=4wid+(x>>2)][slot].
// Split-bf16: v = hi(truncate) + lo(rtn residual); D = Ah*Bl + Al*Bh + Ah*Bh.

#define BLOCK 256
constexpr int TE = 16;
constexpr int N_TILES = 96;
constexpr int PREP_THREADS = N_TILES * 512;               // 49152
constexpr size_t PREP_BYTES = (size_t)N_TILES * 1024 * 2; // 196608

typedef __attribute__((ext_vector_type(8))) short short8;
typedef __attribute__((ext_vector_type(4))) float f32x4;

__device__ __forceinline__ unsigned short f2b(float x) {
  return __builtin_bit_cast(unsigned short, __float2bfloat16(x));
}

__global__ __launch_bounds__(256) void prep_kernel(
    const float* __restrict__ w3_0, const float* __restrict__ w3_1,
    const float* __restrict__ w3_2, const float* __restrict__ w3_3,
    unsigned short* __restrict__ ws)
{
  const int gid = blockIdx.x * 256 + threadIdx.x;
  if (gid >= PREP_THREADS) return;
  const int tid = gid >> 9;            // tile 0..95
  const int l   = gid & 511;
  const int lane = l >> 3, j = l & 7;
  const int x = lane & 15, g = lane >> 4;
  const int m = 8 * g + j;
  const float* w3; int NC, c0;
  if (tid < 16)      { w3 = w3_0; NC = 256; c0 = tid * 16; }
  else if (tid < 32) { w3 = w3_1; NC = 256; c0 = (tid - 16) * 16; }
  else if (tid < 48) { w3 = w3_2; NC = 256; c0 = (tid - 32) * 16; }
  else { const int t3 = tid - 48, co = t3 / 3, kc = t3 % 3;
         w3 = w3_3; NC = 768; c0 = co * 48 + kc * 16; }
  const float v = w3[m * NC + c0 + x];
  const unsigned u = __builtin_bit_cast(unsigned, v);
  ws[tid * 1024 + l] = (unsigned short)(u >> 16);
  ws[tid * 1024 + 512 + l] =
      f2b(v - __builtin_bit_cast(float, u & 0xFFFF0000u));
}

// ---- LDS pool (bytes). PERS whole-kernel; EARLY aliases LATE oacc. ----
// PERS: ssrc@0(64) sdst@64(64) h2hi@128(4096) h2lo@4224(4096)
//       ts0@8320(1280) ts1@9600(3328) ts2@12928(1280) ts3@14208(9344) -> 23552
// EARLY(@23552): eis(128) h1s@23680(8448) sf0@32128(1024) sf1@33152(3072)
//       sb00@36224(64) sb01@36288(192) sb10@36480(192) sb11@36672(1728) ->38400
// LATE(@23552, aliases EARLY): oacc float[16][68] (4352)
constexpr int SMEM_BYTES = 38400;
constexpr int TS3_STRIDE = 146;

// DPP row-rotate (within 16-lane rows) — VALU pipe, no DS traffic.
template<int CTRL>
__device__ __forceinline__ float dpp_mov(float v) {
  int r = __builtin_amdgcn_update_dpp(0, __builtin_bit_cast(int, v),
                                      CTRL, 0xF, 0xF, false);
  return __builtin_bit_cast(float, r);
}
__device__ __forceinline__ float rowsum16(float v) {
  v += dpp_mov<0x121>(v);   // row_ror:1
  v += dpp_mov<0x122>(v);   // row_ror:2
  v += dpp_mov<0x124>(v);   // row_ror:4
  v += dpp_mov<0x128>(v);   // row_ror:8
  return v;                 // all 16 lanes of the row hold the full sum
}

template<bool USE_WS, int NC>
__device__ __forceinline__ void get_bfrag(
    const unsigned short* __restrict__ ws, int tid,
    const float* __restrict__ w3, int c0, int x, int g, int lane,
    short8& Bh, short8& Bl)
{
  if constexpr (USE_WS) {
    const unsigned short* tb = ws + tid * 1024 + lane * 8;
    Bh = *(const short8*)tb;
    Bl = *(const short8*)(tb + 512);
  } else {
    const float* bp = w3 + (8 * g) * NC + c0 + x;
    #pragma unroll
    for (int j = 0; j < 8; ++j) {
      const float v = bp[j * NC];
      const unsigned u = __builtin_bit_cast(unsigned, v);
      Bh[j] = (short)(u >> 16);
      Bl[j] = (short)f2b(v - __builtin_bit_cast(float, u & 0xFFFF0000u));
    }
  }
}

__device__ __forceinline__ f32x4 mfma3(short8 Ah, short8 Al, short8 Bh, short8 Bl) {
  f32x4 d = {0.f, 0.f, 0.f, 0.f};
  d = __builtin_amdgcn_mfma_f32_16x16x32_bf16(Ah, Bl, d, 0, 0, 0);
  d = __builtin_amdgcn_mfma_f32_16x16x32_bf16(Al, Bh, d, 0, 0, 0);
  d = __builtin_amdgcn_mfma_f32_16x16x32_bf16(Ah, Bh, d, 0, 0, 0);
  return d;
}

#define PICK4(v0, v1, v2, v3) \
  (xr == 0 ? (v0) : xr == 1 ? (v1) : xr == 2 ? (v2) : (v3))

template<bool USE_WS>
__global__ __launch_bounds__(BLOCK) void conv_se3_kernel(
    const float* __restrict__ feat0,
    const float* __restrict__ feat1,
    const float* __restrict__ edge_inv,
    const int*   __restrict__ src,
    const int*   __restrict__ dst,
    const float* __restrict__ b00,
    const float* __restrict__ b01,
    const float* __restrict__ b10,
    const float* __restrict__ b11,
    const float* __restrict__ w1_0, const float* __restrict__ bb1_0,
    const float* __restrict__ w2_0, const float* __restrict__ bb2_0,
    const float* __restrict__ w3_0,
    const float* __restrict__ w1_1, const float* __restrict__ bb1_1,
    const float* __restrict__ w2_1, const float* __restrict__ bb2_1,
    const float* __restrict__ w3_1,
    const float* __restrict__ w1_2, const float* __restrict__ bb1_2,
    const float* __restrict__ w2_2, const float* __restrict__ bb2_2,
    const float* __restrict__ w3_2,
    const float* __restrict__ w1_3, const float* __restrict__ bb1_3,
    const float* __restrict__ w2_3, const float* __restrict__ bb2_3,
    const float* __restrict__ w3_3,
    const unsigned short* __restrict__ ws,
    float* __restrict__ out)
{
  __shared__ __align__(16) char smem[SMEM_BYTES];
  int*            ssrc = (int*)(smem + 0);
  int*            sdst = (int*)(smem + 64);
  unsigned short* h2hi = (unsigned short*)(smem + 128);    // [4][16][32]
  unsigned short* h2lo = (unsigned short*)(smem + 4224);   // [4][16][32]
  float*          ts0  = (float*)(smem + 8320);            // [16][20]
  float*          ts1  = (float*)(smem + 9600);            // [16][52]
  float*          ts2  = (float*)(smem + 12928);           // [16][20]
  float*          ts3  = (float*)(smem + 14208);           // [16][146]
  float*          oacc = (float*)(smem + 23552);           // [16][68] (LATE)
  float*          eis  = (float*)(smem + 23552);           // EARLY aliases
  float*          h1s  = (float*)(smem + 23680);           // [4][16][33]
  float*          sf0  = (float*)(smem + 32128);           // [16][16]
  float*          sf1  = (float*)(smem + 33152);           // [16][48]
  float*          sb00 = (float*)(smem + 36224);           // [16]
  float*          sb01 = (float*)(smem + 36288);           // [16][3]
  float*          sb10 = (float*)(smem + 36480);           // [16][3]
  float*          sb11 = (float*)(smem + 36672);           // [16][27]

  const int t    = threadIdx.x;
  const int wid  = t >> 6;
  const int lane = t & 63;
  const int x    = lane & 15;     // MFMA: A-row / B-col / D-col(k)
  const int g    = lane >> 4;     // MFMA: k-chunk / D row-chunk
  const int xr   = x & 3;         // owned edge offset: e = 4g+xr
  const int xq   = x >> 2;        // owned col offset:  co = 4wid+xq
  const int e0   = blockIdx.x * TE;

  // ---- P0: stage per-edge scalars ----
  for (int i = t; i < TE * 2; i += BLOCK) eis[i] = edge_inv[e0 * 2 + i];
  if (t < TE) { ssrc[t] = src[e0 + t]; sdst[t] = dst[e0 + t]; sb00[t] = b00[e0 + t]; }
  for (int i = t; i < TE * 3; i += BLOCK) {
    sb01[i] = b01[e0 * 3 + i];
    sb10[i] = b10[e0 * 3 + i];
  }
  for (int i = t; i < TE * 27; i += BLOCK) sb11[i] = b11[e0 * 27 + i];
  __syncthreads();

  // ---- P1a: h1 = relu(edge_inv @ W1 + b1) -> fp32 LDS ----
  {
    const int combo = t & 127, p = combo >> 5, m = combo & 31, eb = (t >> 7) * 8;
    const float* w1p = p == 0 ? w1_0 : p == 1 ? w1_1 : p == 2 ? w1_2 : w1_3;
    const float* b1p = p == 0 ? bb1_0 : p == 1 ? bb1_1 : p == 2 ? bb1_2 : bb1_3;
    const float wa = w1p[m], wb = w1p[32 + m], bv = b1p[m];
    #pragma unroll
    for (int ee = 0; ee < 8; ++ee) {
      const int ei = eb + ee;
      const float v = fmaf(eis[ei * 2], wa, fmaf(eis[ei * 2 + 1], wb, bv));
      h1s[p * 528 + ei * 33 + m] = v > 0.f ? v : 0.f;
    }
  }
  // ---- P2a: gather source-node features ----
  for (int i = t; i < TE * 16; i += BLOCK) {
    const int ei = i >> 4;
    sf0[ei * 16 + (i & 15)] = feat0[ssrc[ei] * 16 + (i & 15)];
  }
  for (int i = t; i < TE * 48; i += BLOCK) {
    const int ei = i / 48;
    sf1[ei * 48 + i % 48] = feat1[ssrc[ei] * 48 + (i % 48)];
  }
  __syncthreads();

  // ---- P1b: h2 = relu(h1 @ W2 + b2), exact fp32; truncation hi/lo to LDS ----
  {
    const int p = wid;
    const float* w2p = p == 0 ? w2_0 : p == 1 ? w2_1 : p == 2 ? w2_2 : w2_3;
    const float* b2p = p == 0 ? bb2_0 : p == 1 ? bb2_1 : p == 2 ? bb2_2 : bb2_3;
    float acc[8];                 // lane (x,g): edge x, m = 8g..8g+7
    #pragma unroll
    for (int mm = 0; mm < 8; ++mm) acc[mm] = b2p[8 * g + mm];
    #pragma unroll
    for (int i = 0; i < 32; ++i) {
      const float hv = h1s[p * 528 + x * 33 + i];
      const f32x4 wA = *(const f32x4*)(w2p + i * 32 + 8 * g);
      const f32x4 wB = *(const f32x4*)(w2p + i * 32 + 8 * g + 4);
      acc[0] = fmaf(hv, wA[0], acc[0]); acc[1] = fmaf(hv, wA[1], acc[1]);
      acc[2] = fmaf(hv, wA[2], acc[2]); acc[3] = fmaf(hv, wA[3], acc[3]);
      acc[4] = fmaf(hv, wB[0], acc[4]); acc[5] = fmaf(hv, wB[1], acc[5]);
      acc[6] = fmaf(hv, wB[2], acc[6]); acc[7] = fmaf(hv, wB[3], acc[7]);
    }
    short8 hv8, lv8;
    #pragma unroll
    for (int mm = 0; mm < 8; ++mm) {
      const float v = acc[mm] > 0.f ? acc[mm] : 0.f;
      const unsigned u = __builtin_bit_cast(unsigned, v);
      const float hi = __builtin_bit_cast(float, u & 0xFFFF0000u);
      hv8[mm] = (short)(u >> 16);
      lv8[mm] = (short)f2b(v - hi);
    }
    *(short8*)(h2hi + p * 512 + x * 32 + 8 * g) = hv8;
    *(short8*)(h2lo + p * 512 + x * 32 + 8 * g) = lv8;
  }
  // ---- P2b: tmp tensors (fp32) ----
  for (int i = t; i < TE * 16; i += BLOCK) {
    const int ei = i >> 4, k = i & 15;
    ts0[ei * 20 + k] = sf0[ei * 16 + k] * sb00[ei];
    float a = 0.f;
    #pragma unroll
    for (int ii = 0; ii < 3; ++ii)
      a = fmaf(sf1[ei * 48 + k * 3 + ii], sb10[ei * 3 + ii], a);
    ts2[ei * 20 + k] = a;
  }
  for (int i = t; i < TE * 48; i += BLOCK) {
    const int ei = i / 48, r = i % 48, k = r / 3, dd = r % 3;
    ts1[ei * 52 + k * 3 + dd] = sf0[ei * 16 + k] * sb01[ei * 3 + dd];
  }
  for (int i = t; i < TE * 144; i += BLOCK) {
    const int ei = i / 144, r = i % 144, k = r / 3, dd = r % 3, ci = k / 3, f = k % 3;
    float a = 0.f;
    #pragma unroll
    for (int ii = 0; ii < 3; ++ii)
      a = fmaf(sf1[ei * 48 + ci * 3 + ii], sb11[ei * 27 + ii * 9 + f * 3 + dd], a);
    ts3[ei * TS3_STRIDE + k * 3 + dd] = a;
  }
  __syncthreads();   // EARLY dead from here; PERS read-only; oacc writable

  float o0 = 0.f, o1 = 0.f, o2 = 0.f, o3 = 0.f; // lane owns (e=4g+xr, co=4wid+xq)

  // ===== Pairs 0..2 (K=16): tile i -> co = 4wid+i, k = x =====
  #pragma unroll
  for (int p = 0; p < 3; ++p) {
    const short8 Ah = *(const short8*)(h2hi + p * 512 + x * 32 + 8 * g);
    const short8 Al = *(const short8*)(h2lo + p * 512 + x * 32 + 8 * g);
    const float* w3p = p == 0 ? w3_0 : p == 1 ? w3_1 : w3_2;
    const float* tsp = p == 0 ? ts0 : p == 1 ? ts1 : ts2;
    #pragma unroll
    for (int i = 0; i < 4; ++i) {
      const int co = wid * 4 + i;
      short8 Bh, Bl;
      get_bfrag<USE_WS, 256>(ws, p * 16 + co, w3p, co * 16, x, g, lane, Bh, Bl);
      const f32x4 d = mfma3(Ah, Al, Bh, Bl);
      if (p != 1) {   // DO=1 -> slot 0
        float v0 = d[0] * tsp[(4 * g + 0) * 20 + x];
        float v1 = d[1] * tsp[(4 * g + 1) * 20 + x];
        float v2 = d[2] * tsp[(4 * g + 2) * 20 + x];
        float v3 = d[3] * tsp[(4 * g + 3) * 20 + x];
        v0 = rowsum16(v0); v1 = rowsum16(v1); v2 = rowsum16(v2); v3 = rowsum16(v3);
        if (xq == i) o0 += PICK4(v0, v1, v2, v3);
      } else {        // DO=3 -> slots 1..3
        float a0, a1, a2, a3, b0, b1, b2, b3, c0_, c1_, c2_, c3_;
        {
          const float* tp = ts1 + (4 * g + 0) * 52 + x * 3;
          a0 = d[0] * tp[0]; b0 = d[0] * tp[1]; c0_ = d[0] * tp[2];
        }
        {
          const float* tp = ts1 + (4 * g + 1) * 52 + x * 3;
          a1 = d[1] * tp[0]; b1 = d[1] * tp[1]; c1_ = d[1] * tp[2];
        }
        {
          const float* tp = ts1 + (4 * g + 2) * 52 + x * 3;
          a2 = d[2] * tp[0]; b2 = d[2] * tp[1]; c2_ = d[2] * tp[2];
        }
        {
          const float* tp = ts1 + (4 * g + 3) * 52 + x * 3;
          a3 = d[3] * tp[0]; b3 = d[3] * tp[1]; c3_ = d[3] * tp[2];
        }
        a0 = rowsum16(a0); a1 = rowsum16(a1); a2 = rowsum16(a2); a3 = rowsum16(a3);
        b0 = rowsum16(b0); b1 = rowsum16(b1); b2 = rowsum16(b2); b3 = rowsum16(b3);
        c0_ = rowsum16(c0_); c1_ = rowsum16(c1_); c2_ = rowsum16(c2_); c3_ = rowsum16(c3_);
        if (xq == i) {
          o1 += PICK4(a0, a1, a2, a3);
          o2 += PICK4(b0, b1, b2, b3);
          o3 += PICK4(c0_, c1_, c2_, c3_);
        }
      }
    }
  }

  // ===== Pair 3 (K=48): quarter q -> co = 4wid+q, k = kc*16+x =====
  {
    const short8 Ah = *(const short8*)(h2hi + 3 * 512 + x * 32 + 8 * g);
    const short8 Al = *(const short8*)(h2lo + 3 * 512 + x * 32 + 8 * g);
    #pragma unroll
    for (int q = 0; q < 4; ++q) {
      const int co = 4 * wid + q;
      float a0 = 0.f, a1 = 0.f, a2 = 0.f, a3 = 0.f;
      float b0 = 0.f, b1 = 0.f, b2 = 0.f, b3 = 0.f;
      float c0_ = 0.f, c1_ = 0.f, c2_ = 0.f, c3_ = 0.f;
      #pragma unroll
      for (int kc = 0; kc < 3; ++kc) {
        short8 Bh, Bl;
        get_bfrag<USE_WS, 768>(ws, 48 + co * 3 + kc, w3_3,
                               co * 48 + kc * 16, x, g, lane, Bh, Bl);
        const f32x4 d = mfma3(Ah, Al, Bh, Bl);
        const int kb = (kc * 16 + x) * 3;
        {
          const float* tp = ts3 + (4 * g + 0) * TS3_STRIDE + kb;
          a0 = fmaf(d[0], tp[0], a0); b0 = fmaf(d[0], tp[1], b0); c0_ = fmaf(d[0], tp[2], c0_);
        }
        {
          const float* tp = ts3 + (4 * g + 1) * TS3_STRIDE + kb;
          a1 = fmaf(d[1], tp[0], a1); b1 = fmaf(d[1], tp[1], b1); c1_ = fmaf(d[1], tp[2], c1_);
        }
        {
          const float* tp = ts3 + (4 * g + 2) * TS3_STRIDE + kb;
          a2 = fmaf(d[2], tp[0], a2); b2 = fmaf(d[2], tp[1], b2); c2_ = fmaf(d[2], tp[2], c2_);
        }
        {
          const float* tp = ts3 + (4 * g + 3) * TS3_STRIDE + kb;
          a3 = fmaf(d[3], tp[0], a3); b3 = fmaf(d[3], tp[1], b3); c3_ = fmaf(d[3], tp[2], c3_);
        }
      }
      a0 = rowsum16(a0); a1 = rowsum16(a1); a2 = rowsum16(a2); a3 = rowsum16(a3);
      b0 = rowsum16(b0); b1 = rowsum16(b1); b2 = rowsum16(b2); b3 = rowsum16(b3);
      c0_ = rowsum16(c0_); c1_ = rowsum16(c1_); c2_ = rowsum16(c2_); c3_ = rowsum16(c3_);
      if (xq == q) {
        o1 += PICK4(a0, a1, a2, a3);
        o2 += PICK4(b0, b1, b2, b3);
        o3 += PICK4(c0_, c1_, c2_, c3_);
      }
    }
  }

  // ---- transpose through oacc, then r1-style coalesced row atomics ----
  {
    f32x4 ov = {o0, o1, o2, o3};
    *(f32x4*)(oacc + (4 * g + xr) * 68 + (4 * wid + xq) * 4) = ov;
  }
  __syncthreads();
  #pragma unroll
  for (int i = t; i < TE * 64; i += BLOCK) {
    const int e = i >> 6, c = i & 63;
    atomicAdd(&out[(size_t)sdst[e] * 64 + c], oacc[e * 68 + c]);
  }
}

extern "C" void kernel_launch(void* const* d_in, const int* in_sizes, int n_in,
                              void* d_out, int out_size, void* d_ws, size_t ws_size,
                              hipStream_t stream)
{
  const float* feat0    = (const float*)d_in[0];
  const float* feat1    = (const float*)d_in[1];
  const float* edge_inv = (const float*)d_in[2];
  const int*   src      = (const int*)d_in[3];
  const int*   dst      = (const int*)d_in[4];
  const float* b00      = (const float*)d_in[5];
  const float* b01      = (const float*)d_in[6];
  const float* b10      = (const float*)d_in[7];
  const float* b11      = (const float*)d_in[8];
  const float* w1[4]; const float* bb1[4]; const float* w2[4]; const float* bb2[4]; const float* w3[4];
  for (int p = 0; p < 4; ++p) {   // dict order: 00, 01, 10, 11
    w1[p]  = (const float*)d_in[9 + 5 * p + 0];
    bb1[p] = (const float*)d_in[9 + 5 * p + 1];
    w2[p]  = (const float*)d_in[9 + 5 * p + 2];
    bb2[p] = (const float*)d_in[9 + 5 * p + 3];
    w3[p]  = (const float*)d_in[9 + 5 * p + 4];
  }
  float* out = (float*)d_out;
  unsigned short* wsp = (unsigned short*)d_ws;
  const int E = in_sizes[3];   // 160000

  hipMemsetAsync(d_out, 0, (size_t)out_size * sizeof(float), stream);

  const bool use_ws = (ws_size >= PREP_BYTES);   // constant across calls
  if (use_ws) {
    hipLaunchKernelGGL(prep_kernel, dim3((PREP_THREADS + 255) / 256), dim3(256),
                       0, stream, w3[0], w3[1], w3[2], w3[3], wsp);
    hipLaunchKernelGGL((conv_se3_kernel<true>), dim3(E / TE), dim3(BLOCK), 0, stream,
        feat0, feat1, edge_inv, src, dst, b00, b01, b10, b11,
        w1[0], bb1[0], w2[0], bb2[0], w3[0],
        w1[1], bb1[1], w2[1], bb2[1], w3[1],
        w1[2], bb1[2], w2[2], bb2[2], w3[2],
        w1[3], bb1[3], w2[3], bb2[3], w3[3],
        wsp, out);
  } else {
    hipLaunchKernelGGL((conv_se3_kernel<false>), dim3(E / TE), dim3(BLOCK), 0, stream,
        feat0, feat1, edge_inv, src, dst, b00, b01, b10, b11,
        w1[0], bb1[0], w2[0], bb2[0], w3[0],
        w1[1], bb1[1], w2[1], bb2[1], w3[1],
        w1[2], bb1[2], w2[2], bb2[2], w3[2],
        w1[3], bb1[3], w2[3], bb2[3], w3[3],
        wsp, out);
  }
}

// Round 10
// 267.016 us; speedup vs baseline: 3.4138x; 1.3780x over previous
//
#include <hip/hip_runtime.h>
#include <hip/hip_bf16.h>

// ConvSE3 fused — r9-verified epilogue (DPP rotate-reduce, coalesced atomics)
//   + fused P1: h1 built in-register, h2 via split-bf16 MFMA (ws W2 frags)
//   + div/mod-free P2b indexing + 5 blocks/CU LDS budget.
// E=160000, N=10000, C=16, MID=32, TE=16 edges/block.
// Pairs: p0="00"(K=16,slot0) p1="01"(K=16,slots1-3) p2="10"(K=16,slot0)
//        p3="11"(K=48,slots1-3).  rw col = c_out*K + k, k = c_in*nf + f.
// GEMM: D[edge][col] = sum_m A[edge][m] * B[m][col]
//   A-frag lane&15 = row; B-frag lane&15 = col; k = 8*(lane>>4)+j.
//   D: col = lane&15, row = 4*(lane>>4)+reg. [m89-verified]
// Wave wid owns cols co = 4*wid..4*wid+3; lane (x,g) accumulates
//   out[e=4g+(x&3)][co=4wid+(x>>2)][slot] via rowsum16 DPP + PICK4.
// Split-bf16: v = hi(truncate) + lo(rtn residual); D = Ah*Bl + Al*Bh + Ah*Bh.
// ws: 104 tiles x 1024 ushort [hi:512|lo:512], element = lane*8+j.
//   tiles 0..47: W3 p0..p2 (co); 48..95: W3 p3 (co*3+kc); 96..103: W2 (p*2+tt).

#define BLOCK 256
constexpr int TE = 16;
constexpr int N_TILES = 104;
constexpr int PREP_THREADS = N_TILES * 512;               // 53248
constexpr size_t PREP_BYTES = (size_t)N_TILES * 1024 * 2; // 212992

typedef __attribute__((ext_vector_type(8))) short short8;
typedef __attribute__((ext_vector_type(4))) float f32x4;

__device__ __forceinline__ unsigned short f2b(float x) {
  return __builtin_bit_cast(unsigned short, __float2bfloat16(x));
}

__global__ __launch_bounds__(256) void prep_kernel(
    const float* __restrict__ w3_0, const float* __restrict__ w3_1,
    const float* __restrict__ w3_2, const float* __restrict__ w3_3,
    const float* __restrict__ w2_0, const float* __restrict__ w2_1,
    const float* __restrict__ w2_2, const float* __restrict__ w2_3,
    unsigned short* __restrict__ ws)
{
  const int gid = blockIdx.x * 256 + threadIdx.x;
  if (gid >= PREP_THREADS) return;
  const int tid = gid >> 9;            // tile 0..103
  const int l   = gid & 511;
  const int lane = l >> 3, j = l & 7;
  const int x = lane & 15, g = lane >> 4;
  const int m = 8 * g + j;
  const float* mat; int NC, c0;
  if (tid < 16)      { mat = w3_0; NC = 256; c0 = tid * 16; }
  else if (tid < 32) { mat = w3_1; NC = 256; c0 = (tid - 16) * 16; }
  else if (tid < 48) { mat = w3_2; NC = 256; c0 = (tid - 32) * 16; }
  else if (tid < 96) { const int t3 = tid - 48, co = t3 / 3, kc = t3 % 3;
                       mat = w3_3; NC = 768; c0 = co * 48 + kc * 16; }
  else { const int t2 = tid - 96, p = t2 >> 1, tt = t2 & 1;
         mat = p == 0 ? w2_0 : p == 1 ? w2_1 : p == 2 ? w2_2 : w2_3;
         NC = 32; c0 = tt * 16; }
  const float v = mat[m * NC + c0 + x];
  const unsigned u = __builtin_bit_cast(unsigned, v);
  ws[tid * 1024 + l] = (unsigned short)(u >> 16);
  ws[tid * 1024 + 512 + l] =
      f2b(v - __builtin_bit_cast(float, u & 0xFFFF0000u));
}

// ---- LDS pool (bytes). PERS whole-kernel; EARLY aliases LATE oacc. ----
// PERS: ssrc@0(64) sdst@64(64) h2hi@128(4096) h2lo@4224(4096)
//       ts0@8320(1280) ts1@9600(3328) ts2@12928(1280) ts3@14208(9344) -> 23552
// LATE(@23552): oacc float[16][68] (4352) -> 27904
// EARLY(@23552, dead before oacc written): sf0(1024) sf1@24576(3072)
//       sb00@27648(64) sb01@27712(192) sb10@27904(192) sb11@28096(1728) ->29824
constexpr int SMEM_BYTES = 29824;
constexpr int TS3_STRIDE = 146;

// DPP row-rotate (within 16-lane rows) — VALU pipe, no DS traffic.
template<int CTRL>
__device__ __forceinline__ float dpp_mov(float v) {
  int r = __builtin_amdgcn_update_dpp(0, __builtin_bit_cast(int, v),
                                      CTRL, 0xF, 0xF, false);
  return __builtin_bit_cast(float, r);
}
__device__ __forceinline__ float rowsum16(float v) {
  v += dpp_mov<0x121>(v);   // row_ror:1
  v += dpp_mov<0x122>(v);   // row_ror:2
  v += dpp_mov<0x124>(v);   // row_ror:4
  v += dpp_mov<0x128>(v);   // row_ror:8
  return v;                 // all 16 lanes of the row hold the full sum
}

template<bool USE_WS, int NC>
__device__ __forceinline__ void get_bfrag(
    const unsigned short* __restrict__ ws, int tid,
    const float* __restrict__ mat, int c0, int x, int g, int lane,
    short8& Bh, short8& Bl)
{
  if constexpr (USE_WS) {
    const unsigned short* tb = ws + tid * 1024 + lane * 8;
    Bh = *(const short8*)tb;
    Bl = *(const short8*)(tb + 512);
  } else {
    const float* bp = mat + (8 * g) * NC + c0 + x;
    #pragma unroll
    for (int j = 0; j < 8; ++j) {
      const float v = bp[j * NC];
      const unsigned u = __builtin_bit_cast(unsigned, v);
      Bh[j] = (short)(u >> 16);
      Bl[j] = (short)f2b(v - __builtin_bit_cast(float, u & 0xFFFF0000u));
    }
  }
}

__device__ __forceinline__ f32x4 mfma3(short8 Ah, short8 Al, short8 Bh, short8 Bl) {
  f32x4 d = {0.f, 0.f, 0.f, 0.f};
  d = __builtin_amdgcn_mfma_f32_16x16x32_bf16(Ah, Bl, d, 0, 0, 0);
  d = __builtin_amdgcn_mfma_f32_16x16x32_bf16(Al, Bh, d, 0, 0, 0);
  d = __builtin_amdgcn_mfma_f32_16x16x32_bf16(Ah, Bh, d, 0, 0, 0);
  return d;
}

#define PICK4(v0, v1, v2, v3) \
  (xr == 0 ? (v0) : xr == 1 ? (v1) : xr == 2 ? (v2) : (v3))

template<bool USE_WS>
__global__ __launch_bounds__(BLOCK, 5) void conv_se3_kernel(
    const float* __restrict__ feat0,
    const float* __restrict__ feat1,
    const float* __restrict__ edge_inv,
    const int*   __restrict__ src,
    const int*   __restrict__ dst,
    const float* __restrict__ b00,
    const float* __restrict__ b01,
    const float* __restrict__ b10,
    const float* __restrict__ b11,
    const float* __restrict__ w1_0, const float* __restrict__ bb1_0,
    const float* __restrict__ w2_0, const float* __restrict__ bb2_0,
    const float* __restrict__ w3_0,
    const float* __restrict__ w1_1, const float* __restrict__ bb1_1,
    const float* __restrict__ w2_1, const float* __restrict__ bb2_1,
    const float* __restrict__ w3_1,
    const float* __restrict__ w1_2, const float* __restrict__ bb1_2,
    const float* __restrict__ w2_2, const float* __restrict__ bb2_2,
    const float* __restrict__ w3_2,
    const float* __restrict__ w1_3, const float* __restrict__ bb1_3,
    const float* __restrict__ w2_3, const float* __restrict__ bb2_3,
    const float* __restrict__ w3_3,
    const unsigned short* __restrict__ ws,
    float* __restrict__ out)
{
  __shared__ __align__(16) char smem[SMEM_BYTES];
  int*            ssrc = (int*)(smem + 0);
  int*            sdst = (int*)(smem + 64);
  unsigned short* h2hi = (unsigned short*)(smem + 128);    // [4][16][32]
  unsigned short* h2lo = (unsigned short*)(smem + 4224);   // [4][16][32]
  float*          ts0  = (float*)(smem + 8320);            // [16][20]
  float*          ts1  = (float*)(smem + 9600);            // [16][52]
  float*          ts2  = (float*)(smem + 12928);           // [16][20]
  float*          ts3  = (float*)(smem + 14208);           // [16][146]
  float*          oacc = (float*)(smem + 23552);           // [16][68] (LATE)
  float*          sf0  = (float*)(smem + 23552);           // EARLY aliases
  float*          sf1  = (float*)(smem + 24576);           // [16][48]
  float*          sb00 = (float*)(smem + 27648);           // [16]
  float*          sb01 = (float*)(smem + 27712);           // [16][3]
  float*          sb10 = (float*)(smem + 27904);           // [16][3]
  float*          sb11 = (float*)(smem + 28096);           // [16][27]

  const int t    = threadIdx.x;
  const int wid  = t >> 6;
  const int lane = t & 63;
  const int x    = lane & 15;     // MFMA: A-row / B-col / D-col
  const int g    = lane >> 4;     // MFMA: k-chunk / D row-chunk
  const int xr   = x & 3;         // owned edge offset: e = 4g+xr
  const int xq   = x >> 2;        // owned col offset:  co = 4wid+xq
  const int e0   = blockIdx.x * TE;

  // ---- P0: stage per-edge scalars (no eis: edge_inv read direct) ----
  if (t < TE) { ssrc[t] = src[e0 + t]; sdst[t] = dst[e0 + t]; sb00[t] = b00[e0 + t]; }
  for (int i = t; i < TE * 3; i += BLOCK) {
    sb01[i] = b01[e0 * 3 + i];
    sb10[i] = b10[e0 * 3 + i];
  }
  for (int i = t; i < TE * 27; i += BLOCK) sb11[i] = b11[e0 * 27 + i];

  // ---- P1 fused: h1 in registers; h2 = relu(h1@W2+b2) via split MFMA ----
  // Wave p handles pair p; lane (x,g): edge x, m-chunk 8g..8g+7.
  {
    const int p = wid;
    const float* w1p = p == 0 ? w1_0 : p == 1 ? w1_1 : p == 2 ? w1_2 : w1_3;
    const float* b1p = p == 0 ? bb1_0 : p == 1 ? bb1_1 : p == 2 ? bb1_2 : bb1_3;
    const float* w2p = p == 0 ? w2_0 : p == 1 ? w2_1 : p == 2 ? w2_2 : w2_3;
    const float* b2p = p == 0 ? bb2_0 : p == 1 ? bb2_1 : p == 2 ? bb2_2 : bb2_3;
    const float ev0 = edge_inv[(e0 + x) * 2 + 0];
    const float ev1 = edge_inv[(e0 + x) * 2 + 1];
    short8 Ah, Al;
    #pragma unroll
    for (int j = 0; j < 8; ++j) {
      const int m = 8 * g + j;
      float v = fmaf(ev0, w1p[m], fmaf(ev1, w1p[32 + m], b1p[m]));
      v = v > 0.f ? v : 0.f;
      const unsigned u = __builtin_bit_cast(unsigned, v);
      Ah[j] = (short)(u >> 16);
      Al[j] = (short)f2b(v - __builtin_bit_cast(float, u & 0xFFFF0000u));
    }
    #pragma unroll
    for (int tt = 0; tt < 2; ++tt) {
      short8 Bh, Bl;
      get_bfrag<USE_WS, 32>(ws, 96 + p * 2 + tt, w2p, tt * 16, x, g, lane, Bh, Bl);
      const f32x4 d = mfma3(Ah, Al, Bh, Bl);
      const int m = tt * 16 + x;
      const float bv = b2p[m];
      #pragma unroll
      for (int r = 0; r < 4; ++r) {
        const int e = 4 * g + r;
        float v = d[r] + bv;
        v = v > 0.f ? v : 0.f;
        const unsigned u = __builtin_bit_cast(unsigned, v);
        h2hi[p * 512 + e * 32 + m] = (unsigned short)(u >> 16);
        h2lo[p * 512 + e * 32 + m] =
            f2b(v - __builtin_bit_cast(float, u & 0xFFFF0000u));
      }
    }
  }
  __syncthreads();   // ssrc ready for gathers (h2 barrier comes later)

  // ---- P2a: gather source-node features (div-free) ----
  {
    const int ei = t >> 4, c = t & 15;
    sf0[ei * 16 + c] = feat0[ssrc[ei] * 16 + c];
    const int sb = ssrc[ei] * 48;
    sf1[ei * 48 + c]      = feat1[sb + c];
    sf1[ei * 48 + c + 16] = feat1[sb + c + 16];
    sf1[ei * 48 + c + 32] = feat1[sb + c + 32];
  }
  __syncthreads();

  // ---- P2b: tmp tensors (fp32, div-free indexing) ----
  {
    const int ei = t >> 4, k = t & 15;
    const float* sfb = sf1 + ei * 48;
    // ts0 / ts2
    ts0[ei * 20 + k] = sf0[ei * 16 + k] * sb00[ei];
    {
      float a = 0.f;
      #pragma unroll
      for (int ii = 0; ii < 3; ++ii)
        a = fmaf(sfb[k * 3 + ii], sb10[ei * 3 + ii], a);
      ts2[ei * 20 + k] = a;
    }
    // ts1
    {
      const float sv = sf0[ei * 16 + k];
      #pragma unroll
      for (int dd = 0; dd < 3; ++dd)
        ts1[ei * 52 + k * 3 + dd] = sv * sb01[ei * 3 + dd];
    }
    // ts3: k3 = k + 16a, a=0..2; ci=k3/3, f=k3%3 (cheap mul-shift)
    const float* sbb = sb11 + ei * 27;
    float* tsb = ts3 + ei * TS3_STRIDE;
    #pragma unroll
    for (int a = 0; a < 3; ++a) {
      const int k3 = k + 16 * a;
      const int ci = k3 / 3, f = k3 - ci * 3;
      const float s0 = sfb[ci * 3 + 0];
      const float s1 = sfb[ci * 3 + 1];
      const float s2 = sfb[ci * 3 + 2];
      #pragma unroll
      for (int dd = 0; dd < 3; ++dd) {
        float acc = s0 * sbb[f * 3 + dd];
        acc = fmaf(s1, sbb[9 + f * 3 + dd], acc);
        acc = fmaf(s2, sbb[18 + f * 3 + dd], acc);
        tsb[k3 * 3 + dd] = acc;
      }
    }
  }
  __syncthreads();   // EARLY dead from here; h2 ready cross-wave; oacc writable

  float o0 = 0.f, o1 = 0.f, o2 = 0.f, o3 = 0.f; // lane owns (e=4g+xr, co=4wid+xq)

  // ===== Pairs 0..2 (K=16): tile i -> co = 4wid+i, k = x =====
  #pragma unroll
  for (int p = 0; p < 3; ++p) {
    const short8 Ah = *(const short8*)(h2hi + p * 512 + x * 32 + 8 * g);
    const short8 Al = *(const short8*)(h2lo + p * 512 + x * 32 + 8 * g);
    const float* w3p = p == 0 ? w3_0 : p == 1 ? w3_1 : w3_2;
    const float* tsp = p == 0 ? ts0 : p == 1 ? ts1 : ts2;
    #pragma unroll
    for (int i = 0; i < 4; ++i) {
      const int co = wid * 4 + i;
      short8 Bh, Bl;
      get_bfrag<USE_WS, 256>(ws, p * 16 + co, w3p, co * 16, x, g, lane, Bh, Bl);
      const f32x4 d = mfma3(Ah, Al, Bh, Bl);
      if (p != 1) {   // DO=1 -> slot 0
        float v0 = d[0] * tsp[(4 * g + 0) * 20 + x];
        float v1 = d[1] * tsp[(4 * g + 1) * 20 + x];
        float v2 = d[2] * tsp[(4 * g + 2) * 20 + x];
        float v3 = d[3] * tsp[(4 * g + 3) * 20 + x];
        v0 = rowsum16(v0); v1 = rowsum16(v1); v2 = rowsum16(v2); v3 = rowsum16(v3);
        if (xq == i) o0 += PICK4(v0, v1, v2, v3);
      } else {        // DO=3 -> slots 1..3
        float a0, a1, a2, a3, b0, b1, b2, b3, c0_, c1_, c2_, c3_;
        {
          const float* tp = ts1 + (4 * g + 0) * 52 + x * 3;
          a0 = d[0] * tp[0]; b0 = d[0] * tp[1]; c0_ = d[0] * tp[2];
        }
        {
          const float* tp = ts1 + (4 * g + 1) * 52 + x * 3;
          a1 = d[1] * tp[0]; b1 = d[1] * tp[1]; c1_ = d[1] * tp[2];
        }
        {
          const float* tp = ts1 + (4 * g + 2) * 52 + x * 3;
          a2 = d[2] * tp[0]; b2 = d[2] * tp[1]; c2_ = d[2] * tp[2];
        }
        {
          const float* tp = ts1 + (4 * g + 3) * 52 + x * 3;
          a3 = d[3] * tp[0]; b3 = d[3] * tp[1]; c3_ = d[3] * tp[2];
        }
        a0 = rowsum16(a0); a1 = rowsum16(a1); a2 = rowsum16(a2); a3 = rowsum16(a3);
        b0 = rowsum16(b0); b1 = rowsum16(b1); b2 = rowsum16(b2); b3 = rowsum16(b3);
        c0_ = rowsum16(c0_); c1_ = rowsum16(c1_); c2_ = rowsum16(c2_); c3_ = rowsum16(c3_);
        if (xq == i) {
          o1 += PICK4(a0, a1, a2, a3);
          o2 += PICK4(b0, b1, b2, b3);
          o3 += PICK4(c0_, c1_, c2_, c3_);
        }
      }
    }
  }

  // ===== Pair 3 (K=48): quarter q -> co = 4wid+q, k = kc*16+x =====
  {
    const short8 Ah = *(const short8*)(h2hi + 3 * 512 + x * 32 + 8 * g);
    const short8 Al = *(const short8*)(h2lo + 3 * 512 + x * 32 + 8 * g);
    #pragma unroll
    for (int q = 0; q < 4; ++q) {
      const int co = 4 * wid + q;
      float a0 = 0.f, a1 = 0.f, a2 = 0.f, a3 = 0.f;
      float b0 = 0.f, b1 = 0.f, b2 = 0.f, b3 = 0.f;
      float c0_ = 0.f, c1_ = 0.f, c2_ = 0.f, c3_ = 0.f;
      #pragma unroll
      for (int kc = 0; kc < 3; ++kc) {
        short8 Bh, Bl;
        get_bfrag<USE_WS, 768>(ws, 48 + co * 3 + kc, w3_3,
                               co * 48 + kc * 16, x, g, lane, Bh, Bl);
        const f32x4 d = mfma3(Ah, Al, Bh, Bl);
        const int kb = (kc * 16 + x) * 3;
        {
          const float* tp = ts3 + (4 * g + 0) * TS3_STRIDE + kb;
          a0 = fmaf(d[0], tp[0], a0); b0 = fmaf(d[0], tp[1], b0); c0_ = fmaf(d[0], tp[2], c0_);
        }
        {
          const float* tp = ts3 + (4 * g + 1) * TS3_STRIDE + kb;
          a1 = fmaf(d[1], tp[0], a1); b1 = fmaf(d[1], tp[1], b1); c1_ = fmaf(d[1], tp[2], c1_);
        }
        {
          const float* tp = ts3 + (4 * g + 2) * TS3_STRIDE + kb;
          a2 = fmaf(d[2], tp[0], a2); b2 = fmaf(d[2], tp[1], b2); c2_ = fmaf(d[2], tp[2], c2_);
        }
        {
          const float* tp = ts3 + (4 * g + 3) * TS3_STRIDE + kb;
          a3 = fmaf(d[3], tp[0], a3); b3 = fmaf(d[3], tp[1], b3); c3_ = fmaf(d[3], tp[2], c3_);
        }
      }
      a0 = rowsum16(a0); a1 = rowsum16(a1); a2 = rowsum16(a2); a3 = rowsum16(a3);
      b0 = rowsum16(b0); b1 = rowsum16(b1); b2 = rowsum16(b2); b3 = rowsum16(b3);
      c0_ = rowsum16(c0_); c1_ = rowsum16(c1_); c2_ = rowsum16(c2_); c3_ = rowsum16(c3_);
      if (xq == q) {
        o1 += PICK4(a0, a1, a2, a3);
        o2 += PICK4(b0, b1, b2, b3);
        o3 += PICK4(c0_, c1_, c2_, c3_);
      }
    }
  }

  // ---- transpose through oacc, then coalesced row atomics ----
  {
    f32x4 ov = {o0, o1, o2, o3};
    *(f32x4*)(oacc + (4 * g + xr) * 68 + (4 * wid + xq) * 4) = ov;
  }
  __syncthreads();
  {
    const int c = t & 63, eb = t >> 6;
    #pragma unroll
    for (int ii = 0; ii < 4; ++ii) {
      const int e = eb + 4 * ii;
      atomicAdd(&out[(size_t)sdst[e] * 64 + c], oacc[e * 68 + c]);
    }
  }
}

extern "C" void kernel_launch(void* const* d_in, const int* in_sizes, int n_in,
                              void* d_out, int out_size, void* d_ws, size_t ws_size,
                              hipStream_t stream)
{
  const float* feat0    = (const float*)d_in[0];
  const float* feat1    = (const float*)d_in[1];
  const float* edge_inv = (const float*)d_in[2];
  const int*   src      = (const int*)d_in[3];
  const int*   dst      = (const int*)d_in[4];
  const float* b00      = (const float*)d_in[5];
  const float* b01      = (const float*)d_in[6];
  const float* b10      = (const float*)d_in[7];
  const float* b11      = (const float*)d_in[8];
  const float* w1[4]; const float* bb1[4]; const float* w2[4]; const float* bb2[4]; const float* w3[4];
  for (int p = 0; p < 4; ++p) {   // dict order: 00, 01, 10, 11
    w1[p]  = (const float*)d_in[9 + 5 * p + 0];
    bb1[p] = (const float*)d_in[9 + 5 * p + 1];
    w2[p]  = (const float*)d_in[9 + 5 * p + 2];
    bb2[p] = (const float*)d_in[9 + 5 * p + 3];
    w3[p]  = (const float*)d_in[9 + 5 * p + 4];
  }
  float* out = (float*)d_out;
  unsigned short* wsp = (unsigned short*)d_ws;
  const int E = in_sizes[3];   // 160000

  hipMemsetAsync(d_out, 0, (size_t)out_size * sizeof(float), stream);

  const bool use_ws = (ws_size >= PREP_BYTES);   // constant across calls
  if (use_ws) {
    hipLaunchKernelGGL(prep_kernel, dim3((PREP_THREADS + 255) / 256), dim3(256),
                       0, stream, w3[0], w3[1], w3[2], w3[3],
                       w2[0], w2[1], w2[2], w2[3], wsp);
    hipLaunchKernelGGL((conv_se3_kernel<true>), dim3(E / TE), dim3(BLOCK), 0, stream,
        feat0, feat1, edge_inv, src, dst, b00, b01, b10, b11,
        w1[0], bb1[0], w2[0], bb2[0], w3[0],
        w1[1], bb1[1], w2[1], bb2[1], w3[1],
        w1[2], bb1[2], w2[2], bb2[2], w3[2],
        w1[3], bb1[3], w2[3], bb2[3], w3[3],
        wsp, out);
  } else {
    hipLaunchKernelGGL((conv_se3_kernel<false>), dim3(E / TE), dim3(BLOCK), 0, stream,
        feat0, feat1, edge_inv, src, dst, b00, b01, b10, b11,
        w1[0], bb1[0], w2[0], bb2[0], w3[0],
        w1[1], bb1[1], w2[1], bb2[1], w3[1],
        w1[2], bb1[2], w2[2], bb2[2], w3[2],
        w1[3], bb1[3], w2[3], bb2[3], w3[3],
        wsp, out);
  }
}